// Round 4
// baseline (1258.171 us; speedup 1.0000x reference)
//
#include <hip/hip_runtime.h>
#include <hip/hip_bf16.h>
#include <math.h>

#define BB   64
#define NN   64
#define HH   128
#define OBS_ 128
#define AA   16
#define BN_  4096
#define NM   63
#define G3   384
#define G4   512
#define GKC  16

__device__ __forceinline__ float sigf(float x) { return 1.0f / (1.0f + expf(-x)); }

// ---------------- generic C = A@B^T (+ A2@B2^T) (+bias) (+relu), tile 64x64, K=128 ----
template<bool DUAL, bool RELU, bool BIAS>
__global__ __launch_bounds__(256)
void gemm_tn(const float* __restrict__ A, int lda,
             const float* __restrict__ B, int ldb,
             const float* __restrict__ A2, int lda2,
             const float* __restrict__ B2, int ldb2,
             const float* __restrict__ bias,
             float* __restrict__ C, int ldc, int K)
{
    __shared__ float As[32][68];
    __shared__ float Bs[32][68];
    const int t = threadIdx.x;
    const int tx = t & 15, ty = t >> 4;
    const int row0 = blockIdx.y * 64, col0 = blockIdx.x * 64;
    const int lm = t >> 2;           // 0..63
    const int lk = (t & 3) * 8;      // 0,8,16,24
    float acc[4][4] = {};
    const int npass = DUAL ? 2 : 1;
    for (int pass = 0; pass < npass; ++pass) {
        const float* Ap = pass ? A2 : A; const int ldap = pass ? lda2 : lda;
        const float* Bp = pass ? B2 : B; const int ldbp = pass ? ldb2 : ldb;
        for (int k0 = 0; k0 < K; k0 += 32) {
            __syncthreads();
            {
                const float* srcA = Ap + (size_t)(row0 + lm) * ldap + k0 + lk;
                float4 a0 = *(const float4*)(srcA);
                float4 a1 = *(const float4*)(srcA + 4);
                As[lk + 0][lm] = a0.x; As[lk + 1][lm] = a0.y; As[lk + 2][lm] = a0.z; As[lk + 3][lm] = a0.w;
                As[lk + 4][lm] = a1.x; As[lk + 5][lm] = a1.y; As[lk + 6][lm] = a1.z; As[lk + 7][lm] = a1.w;
                const float* srcB = Bp + (size_t)(col0 + lm) * ldbp + k0 + lk;
                float4 b0 = *(const float4*)(srcB);
                float4 b1 = *(const float4*)(srcB + 4);
                Bs[lk + 0][lm] = b0.x; Bs[lk + 1][lm] = b0.y; Bs[lk + 2][lm] = b0.z; Bs[lk + 3][lm] = b0.w;
                Bs[lk + 4][lm] = b1.x; Bs[lk + 5][lm] = b1.y; Bs[lk + 6][lm] = b1.z; Bs[lk + 7][lm] = b1.w;
            }
            __syncthreads();
            #pragma unroll
            for (int k = 0; k < 32; ++k) {
                float av[4], bv[4];
                *(float4*)av = *(const float4*)&As[k][ty * 4];
                *(float4*)bv = *(const float4*)&Bs[k][tx * 4];
                #pragma unroll
                for (int i = 0; i < 4; ++i)
                    #pragma unroll
                    for (int j = 0; j < 4; ++j)
                        acc[i][j] = fmaf(av[i], bv[j], acc[i][j]);
            }
        }
    }
    #pragma unroll
    for (int i = 0; i < 4; ++i) {
        const int r = row0 + ty * 4 + i;
        const int c = col0 + tx * 4;
        float vv[4];
        #pragma unroll
        for (int j = 0; j < 4; ++j) {
            float x = acc[i][j];
            if (BIAS) x += bias[c + j];
            if (RELU) x = fmaxf(x, 0.0f);
            vv[j] = x;
        }
        *(float4*)&C[(size_t)r * ldc + c] = *(float4*)vv;
    }
}

// ---------------- small prep kernels ----------------
__global__ void prep_hprev(const float* __restrict__ lstm_h, const float* __restrict__ masks,
                           float* __restrict__ hprev)
{
    int i = blockIdx.x * 256 + threadIdx.x;
    hprev[i] = lstm_h[i] * masks[i >> 7];
}

__global__ void transpose_whh(const float* __restrict__ Wf, const float* __restrict__ Wb,
                              float* __restrict__ Tf, float* __restrict__ Tb)
{
    int i = blockIdx.x * 256 + threadIdx.x;
    if (i < G3 * HH) {
        int o = i >> 7, k = i & 127;
        Tf[k * G3 + o] = Wf[i];
        Tb[k * G3 + o] = Wb[i];
    }
}

__global__ void lstm_pointwise(const float* __restrict__ gates,
                               const float* __restrict__ bih, const float* __restrict__ bhh,
                               const float* __restrict__ lstm_c, const float* __restrict__ masks,
                               float* __restrict__ h,
                               float* __restrict__ out_h, float* __restrict__ out_c)
{
    int idx = blockIdx.x * 256 + threadIdx.x;
    int r = idx >> 7, c = idx & 127;
    const float* g = gates + (size_t)r * G4;
    float gi = g[c]        + bih[c]        + bhh[c];
    float gf = g[128 + c]  + bih[128 + c]  + bhh[128 + c];
    float gg = g[256 + c]  + bih[256 + c]  + bhh[256 + c];
    float go = g[384 + c]  + bih[384 + c]  + bhh[384 + c];
    float cprev = lstm_c[idx] * masks[r];
    float cn = sigf(gf) * cprev + sigf(gi) * tanhf(gg);
    float hn = sigf(go) * tanhf(cn);
    h[idx] = hn;
    out_h[idx] = hn;
    out_c[idx] = cn;
}

// ---------------- persistent bidirectional GRU scan ----------------
// grid: 256 blocks (128 fwd + 128 bwd), 512 threads, 32 rows/block (same batch b)
__global__ __launch_bounds__(512)
void gru_scan(const float* __restrict__ WhhTf, const float* __restrict__ WhhTb,
              const float* __restrict__ bhhf, const float* __restrict__ bhhb,
              const float* __restrict__ Uf, const float* __restrict__ Vf,
              const float* __restrict__ Ub, const float* __restrict__ Vb,
              const float* __restrict__ Whard,
              float* __restrict__ partF, float* __restrict__ partB)
{
    __shared__ float hsh[32][132];        // h state [row][c], padded
    __shared__ float wch[GKC][G3];        // WhhT k-chunk [k][o]
    __shared__ float wh[2][HH];           // W_hard slice for this direction
    __shared__ float pred[32][16][2];     // logit partials

    const int t = threadIdx.x;
    const int dir = blockIdx.x >> 7;
    const int blk = blockIdx.x & 127;
    const int r0 = blk * 32;
    const int bbx = r0 >> 6;
    const int n0 = r0 & 63;

    const float* WhhT = dir ? WhhTb : WhhTf;
    const float* bhh  = dir ? bhhb  : bhhf;
    const float* U    = dir ? Ub    : Uf;
    const float* V    = dir ? Vb    : Vf;
    float* part       = dir ? partB : partF;

    const int cg = t & 31;
    const int rg = t >> 5;               // 0..15, rows rg*2 .. rg*2+1
    const int c0 = cg * 4;

    for (int i = t; i < 32 * 132; i += 512) ((float*)hsh)[i] = 0.0f;
    for (int i = t; i < 2 * HH; i += 512)
        wh[i >> 7][i & 127] = Whard[(i >> 7) * 256 + dir * HH + (i & 127)];

    float bh[3][4];
    #pragma unroll
    for (int g = 0; g < 3; ++g)
        #pragma unroll
        for (int j = 0; j < 4; ++j) bh[g][j] = bhh[g * HH + c0 + j];

    float hreg[2][4] = {};
    __syncthreads();

    for (int s = 0; s < NM; ++s) {
        const int tt = dir ? (NM - 1 - s) : s;
        float acc[2][3][4] = {};
        for (int k0 = 0; k0 < HH; k0 += GKC) {
            __syncthreads();
            {   // stage WhhT[k0:k0+16][0:384] = 6144 floats = 1536 float4 / 512 threads
                const float4* src = (const float4*)(WhhT + (size_t)k0 * G3);
                float4* dst = (float4*)&wch[0][0];
                #pragma unroll
                for (int i = 0; i < 3; ++i) dst[t + i * 512] = src[t + i * 512];
            }
            __syncthreads();
            #pragma unroll
            for (int k = 0; k < GKC; ++k) {
                const float hv0 = hsh[rg * 2 + 0][k0 + k];
                const float hv1 = hsh[rg * 2 + 1][k0 + k];
                float wr[4], wz[4], wn[4];
                *(float4*)wr = *(const float4*)&wch[k][c0];
                *(float4*)wz = *(const float4*)&wch[k][HH + c0];
                *(float4*)wn = *(const float4*)&wch[k][2 * HH + c0];
                #pragma unroll
                for (int j = 0; j < 4; ++j) {
                    acc[0][0][j] = fmaf(hv0, wr[j], acc[0][0][j]);
                    acc[0][1][j] = fmaf(hv0, wz[j], acc[0][1][j]);
                    acc[0][2][j] = fmaf(hv0, wn[j], acc[0][2][j]);
                    acc[1][0][j] = fmaf(hv1, wr[j], acc[1][0][j]);
                    acc[1][1][j] = fmaf(hv1, wz[j], acc[1][1][j]);
                    acc[1][2][j] = fmaf(hv1, wn[j], acc[1][2][j]);
                }
            }
        }
        __syncthreads();   // all matmul reads of hsh done
        #pragma unroll
        for (int ri = 0; ri < 2; ++ri) {
            const int row = rg * 2 + ri;
            const int R = r0 + row;
            const int n = n0 + row;
            const int vrow = (bbx << 6) + tt + (tt >= n ? 1 : 0);
            const float* Ur = U + (size_t)R * G3 + c0;
            const float* Vr = V + (size_t)vrow * G3 + c0;
            float ur[4], uz[4], un[4], vr_[4], vz_[4], vn_[4];
            *(float4*)ur  = *(const float4*)(Ur);
            *(float4*)uz  = *(const float4*)(Ur + HH);
            *(float4*)un  = *(const float4*)(Ur + 2 * HH);
            *(float4*)vr_ = *(const float4*)(Vr);
            *(float4*)vz_ = *(const float4*)(Vr + HH);
            *(float4*)vn_ = *(const float4*)(Vr + 2 * HH);
            #pragma unroll
            for (int j = 0; j < 4; ++j) {
                float rr  = sigf(ur[j] + vr_[j] + acc[ri][0][j] + bh[0][j]);
                float zz  = sigf(uz[j] + vz_[j] + acc[ri][1][j] + bh[1][j]);
                float nn2 = tanhf(un[j] + vn_[j] + rr * (acc[ri][2][j] + bh[2][j]));
                float hn  = (1.0f - zz) * nn2 + zz * hreg[ri][j];
                hreg[ri][j] = hn;
                hsh[row][c0 + j] = hn;
            }
        }
        __syncthreads();   // hsh updated
        {   // partial logits: thread -> (row, 8-wide segment)
            const int prow = t >> 4, seg = t & 15;
            float h8[8];
            *(float4*)h8       = *(const float4*)&hsh[prow][seg * 8];
            *(float4*)(h8 + 4) = *(const float4*)&hsh[prow][seg * 8 + 4];
            float p0 = 0.0f, p1 = 0.0f;
            #pragma unroll
            for (int jj = 0; jj < 8; ++jj) {
                p0 = fmaf(h8[jj], wh[0][seg * 8 + jj], p0);
                p1 = fmaf(h8[jj], wh[1][seg * 8 + jj], p1);
            }
            pred[prow][seg][0] = p0;
            pred[prow][seg][1] = p1;
        }
        __syncthreads();
        if (t < 64) {
            const int prow = t >> 1, c = t & 1;
            float ssum = 0.0f;
            #pragma unroll
            for (int sg2 = 0; sg2 < 16; ++sg2) ssum += pred[prow][sg2][c];
            part[((size_t)(r0 + prow) * NM + tt) * 2 + c] = ssum;
        }
    }
}

// ---------------- hard gate + soft attention + action head ----------------
__global__ __launch_bounds__(128)
void attn_final(const float* __restrict__ h, const float* __restrict__ q,
                const float* __restrict__ kk,
                const float* __restrict__ partF, const float* __restrict__ partB,
                const float* __restrict__ bhard, const float* __restrict__ gum,
                const float* __restrict__ Wact, const float* __restrict__ bact,
                float* __restrict__ out_act, float* __restrict__ out_alp)
{
    const int r = blockIdx.x;
    const int bbx = r >> 6, n = r & 63;
    const int t = threadIdx.x;
    __shared__ float qsh[HH], wsh[NM], shh[HH], shx[HH];
    if (t < HH) { qsh[t] = q[(size_t)r * HH + t]; shh[t] = h[(size_t)r * HH + t]; }
    __syncthreads();
    if (t < 64) {
        float sc = -INFINITY;
        float hardv = 0.0f;
        if (t < NM) {
            const int idxm = t + (t >= n ? 1 : 0);
            const float4* kr = (const float4*)(kk + (size_t)((bbx << 6) + idxm) * HH);
            float s = 0.0f;
            #pragma unroll
            for (int j4 = 0; j4 < 32; ++j4) {
                float4 kv = kr[j4];
                float4 qv = *(const float4*)&qsh[j4 * 4];
                s += kv.x * qv.x + kv.y * qv.y + kv.z * qv.z + kv.w * qv.w;
            }
            sc = s * 0.088388347648318447f;   // 1/sqrt(128)
            const float2 pf = *(const float2*)(partF + ((size_t)r * NM + t) * 2);
            const float2 pb = *(const float2*)(partB + ((size_t)r * NM + t) * 2);
            const float2 gv = *(const float2*)(gum + ((size_t)r * NM + t) * 2);
            const float l0 = pf.x + pb.x + bhard[0] + gv.x;
            const float l1 = pf.y + pb.y + bhard[1] + gv.y;
            hardv = (l1 > l0) ? 1.0f : 0.0f;
        }
        float mx = sc;
        #pragma unroll
        for (int d = 32; d; d >>= 1) mx = fmaxf(mx, __shfl_xor(mx, d, 64));
        const float e = (t < NM) ? expf(sc - mx) : 0.0f;
        float sum = e;
        #pragma unroll
        for (int d = 32; d; d >>= 1) sum += __shfl_xor(sum, d, 64);
        if (t < NM) wsh[t] = hardv * e / sum;
    }
    __syncthreads();
    {
        const int j = t;
        float x = 0.0f;
        for (int m = 0; m < NM; ++m) {
            const int idxm = m + (m >= n ? 1 : 0);
            x = fmaf(wsh[m], h[(size_t)((bbx << 6) + idxm) * HH + j], x);
        }
        shx[j] = x;
    }
    __syncthreads();
    if (t < 16) {
        const float* wa = Wact + (size_t)t * 256;
        float acc = bact[t];
        #pragma unroll
        for (int j4 = 0; j4 < 32; ++j4) {
            float4 w1 = *(const float4*)&wa[j4 * 4];
            float4 hv = *(const float4*)&shh[j4 * 4];
            float4 w2 = *(const float4*)&wa[128 + j4 * 4];
            float4 xv = *(const float4*)&shx[j4 * 4];
            acc += w1.x * hv.x + w1.y * hv.y + w1.z * hv.z + w1.w * hv.w
                 + w2.x * xv.x + w2.y * xv.y + w2.z * xv.z + w2.w * xv.w;
        }
        float mx = acc; int am = t;
        #pragma unroll
        for (int d = 8; d; d >>= 1) {
            const float om = __shfl_xor(mx, d, 16);
            const int   oa = __shfl_xor(am, d, 16);
            if (om > mx || (om == mx && oa < am)) { mx = om; am = oa; }
        }
        const float e = expf(acc - mx);
        float sum = e;
        #pragma unroll
        for (int d = 8; d; d >>= 1) sum += __shfl_xor(sum, d, 16);
        if (t == 0) {
            out_act[r] = (float)am;
            out_alp[r] = -logf(sum);
        }
    }
}

// ---------------- launch ----------------
extern "C" void kernel_launch(void* const* d_in, const int* in_sizes, int n_in,
                              void* d_out, int out_size, void* d_ws, size_t ws_size,
                              hipStream_t stream)
{
    const float* obs    = (const float*)d_in[0];
    const float* lstm_h = (const float*)d_in[1];
    const float* lstm_c = (const float*)d_in[2];
    const float* masks  = (const float*)d_in[3];
    const float* W_enc  = (const float*)d_in[4];
    const float* b_enc  = (const float*)d_in[5];
    const float* lWih   = (const float*)d_in[6];
    const float* lWhh   = (const float*)d_in[7];
    const float* lbih   = (const float*)d_in[8];
    const float* lbhh   = (const float*)d_in[9];
    const float* gWihf  = (const float*)d_in[10];
    const float* gWhhf  = (const float*)d_in[11];
    const float* gbihf  = (const float*)d_in[12];
    const float* gbhhf  = (const float*)d_in[13];
    const float* gWihb  = (const float*)d_in[14];
    const float* gWhhb  = (const float*)d_in[15];
    const float* gbihb  = (const float*)d_in[16];
    const float* gbhhb  = (const float*)d_in[17];
    const float* Whard  = (const float*)d_in[18];
    const float* bhard  = (const float*)d_in[19];
    const float* Wq     = (const float*)d_in[20];
    const float* Wk     = (const float*)d_in[21];
    const float* Wact   = (const float*)d_in[22];
    const float* bact   = (const float*)d_in[23];
    const float* gum    = (const float*)d_in[24];

    float* W = (float*)d_ws;
    float* h     = W; W += (size_t)BN_ * HH;
    float* hprev = W; W += (size_t)BN_ * HH;
    float* henc  = W; W += (size_t)BN_ * HH;
    float* gates = W; W += (size_t)BN_ * G4;
    float* Uf    = W; W += (size_t)BN_ * G3;
    float* Vf    = W; W += (size_t)BN_ * G3;
    float* Ub    = W; W += (size_t)BN_ * G3;
    float* Vb    = W; W += (size_t)BN_ * G3;
    float* WTf   = W; W += (size_t)HH * G3;
    float* WTb   = W; W += (size_t)HH * G3;
    float* partF = W; W += (size_t)BN_ * NM * 2;
    float* partB = W; W += (size_t)BN_ * NM * 2;
    float* qq    = W; W += (size_t)BN_ * HH;
    float* kk    = W; W += (size_t)BN_ * HH;

    float* out_f   = (float*)d_out;
    float* out_act = out_f;                       // 4096
    float* out_alp = out_act + BN_;               // 4096
    float* out_h   = out_alp + BN_;               // 4096*128
    float* out_c   = out_h + (size_t)BN_ * HH;    // 4096*128

    prep_hprev<<<BN_ * HH / 256, 256, 0, stream>>>(lstm_h, masks, hprev);
    transpose_whh<<<(HH * G3 + 255) / 256, 256, 0, stream>>>(gWhhf, gWhhb, WTf, WTb);
    gemm_tn<false, true, true><<<dim3(HH / 64, BN_ / 64), 256, 0, stream>>>(
        obs, OBS_, W_enc, OBS_, nullptr, 0, nullptr, 0, b_enc, henc, HH, OBS_);
    gemm_tn<true, false, false><<<dim3(G4 / 64, BN_ / 64), 256, 0, stream>>>(
        henc, HH, lWih, HH, hprev, HH, lWhh, HH, nullptr, gates, G4, HH);
    lstm_pointwise<<<BN_ * HH / 256, 256, 0, stream>>>(gates, lbih, lbhh, lstm_c, masks,
                                                       h, out_h, out_c);
    gemm_tn<false, false, true><<<dim3(G3 / 64, BN_ / 64), 256, 0, stream>>>(
        h, HH, gWihf, 2 * HH, nullptr, 0, nullptr, 0, gbihf, Uf, G3, HH);
    gemm_tn<false, false, false><<<dim3(G3 / 64, BN_ / 64), 256, 0, stream>>>(
        h, HH, gWihf + HH, 2 * HH, nullptr, 0, nullptr, 0, nullptr, Vf, G3, HH);
    gemm_tn<false, false, true><<<dim3(G3 / 64, BN_ / 64), 256, 0, stream>>>(
        h, HH, gWihb, 2 * HH, nullptr, 0, nullptr, 0, gbihb, Ub, G3, HH);
    gemm_tn<false, false, false><<<dim3(G3 / 64, BN_ / 64), 256, 0, stream>>>(
        h, HH, gWihb + HH, 2 * HH, nullptr, 0, nullptr, 0, nullptr, Vb, G3, HH);
    gemm_tn<false, false, false><<<dim3(HH / 64, BN_ / 64), 256, 0, stream>>>(
        h, HH, Wq, HH, nullptr, 0, nullptr, 0, nullptr, qq, HH, HH);
    gemm_tn<false, false, false><<<dim3(HH / 64, BN_ / 64), 256, 0, stream>>>(
        h, HH, Wk, HH, nullptr, 0, nullptr, 0, nullptr, kk, HH, HH);
    gru_scan<<<256, 512, 0, stream>>>(WTf, WTb, gbhhf, gbhhb, Uf, Vf, Ub, Vb,
                                      Whard, partF, partB);
    attn_final<<<BN_, 128, 0, stream>>>(h, qq, kk, partF, partB, bhard, gum,
                                        Wact, bact, out_act, out_alp);
}

// Round 5
// 536.603 us; speedup vs baseline: 2.3447x; 2.3447x over previous
//
#include <hip/hip_runtime.h>
#include <hip/hip_bf16.h>
#include <math.h>

#define BB   64
#define NN   64
#define HH   128
#define OBS_ 128
#define AA   16
#define BN_  4096
#define NM   63
#define G3   384
#define G4   512
#define LDSW 144   // ushort stride for h planes (mult of 8 -> 16B aligned rows)

typedef _Float16 f16x8 __attribute__((ext_vector_type(8)));
typedef float    f32x4 __attribute__((ext_vector_type(4)));

__device__ __forceinline__ float sigf(float x) { return 1.0f / (1.0f + expf(-x)); }

__device__ __forceinline__ unsigned short h2u(_Float16 h) {
    union { _Float16 f; unsigned short u; } cv; cv.f = h; return cv.u;
}

// ---------------- generic C = A@B^T (+ A2@B2^T) (+bias) (+relu), tile 64x64, K=128 ----
template<bool DUAL, bool RELU, bool BIAS>
__global__ __launch_bounds__(256)
void gemm_tn(const float* __restrict__ A, int lda,
             const float* __restrict__ B, int ldb,
             const float* __restrict__ A2, int lda2,
             const float* __restrict__ B2, int ldb2,
             const float* __restrict__ bias,
             float* __restrict__ C, int ldc, int K)
{
    __shared__ float As[32][68];
    __shared__ float Bs[32][68];
    const int t = threadIdx.x;
    const int tx = t & 15, ty = t >> 4;
    const int row0 = blockIdx.y * 64, col0 = blockIdx.x * 64;
    const int lm = t >> 2;           // 0..63
    const int lk = (t & 3) * 8;      // 0,8,16,24
    float acc[4][4] = {};
    const int npass = DUAL ? 2 : 1;
    for (int pass = 0; pass < npass; ++pass) {
        const float* Ap = pass ? A2 : A; const int ldap = pass ? lda2 : lda;
        const float* Bp = pass ? B2 : B; const int ldbp = pass ? ldb2 : ldb;
        for (int k0 = 0; k0 < K; k0 += 32) {
            __syncthreads();
            {
                const float* srcA = Ap + (size_t)(row0 + lm) * ldap + k0 + lk;
                float4 a0 = *(const float4*)(srcA);
                float4 a1 = *(const float4*)(srcA + 4);
                As[lk + 0][lm] = a0.x; As[lk + 1][lm] = a0.y; As[lk + 2][lm] = a0.z; As[lk + 3][lm] = a0.w;
                As[lk + 4][lm] = a1.x; As[lk + 5][lm] = a1.y; As[lk + 6][lm] = a1.z; As[lk + 7][lm] = a1.w;
                const float* srcB = Bp + (size_t)(col0 + lm) * ldbp + k0 + lk;
                float4 b0 = *(const float4*)(srcB);
                float4 b1 = *(const float4*)(srcB + 4);
                Bs[lk + 0][lm] = b0.x; Bs[lk + 1][lm] = b0.y; Bs[lk + 2][lm] = b0.z; Bs[lk + 3][lm] = b0.w;
                Bs[lk + 4][lm] = b1.x; Bs[lk + 5][lm] = b1.y; Bs[lk + 6][lm] = b1.z; Bs[lk + 7][lm] = b1.w;
            }
            __syncthreads();
            #pragma unroll
            for (int k = 0; k < 32; ++k) {
                float av[4], bv[4];
                *(float4*)av = *(const float4*)&As[k][ty * 4];
                *(float4*)bv = *(const float4*)&Bs[k][tx * 4];
                #pragma unroll
                for (int i = 0; i < 4; ++i)
                    #pragma unroll
                    for (int j = 0; j < 4; ++j)
                        acc[i][j] = fmaf(av[i], bv[j], acc[i][j]);
            }
        }
    }
    #pragma unroll
    for (int i = 0; i < 4; ++i) {
        const int r = row0 + ty * 4 + i;
        const int c = col0 + tx * 4;
        float vv[4];
        #pragma unroll
        for (int j = 0; j < 4; ++j) {
            float x = acc[i][j];
            if (BIAS) x += bias[c + j];
            if (RELU) x = fmaxf(x, 0.0f);
            vv[j] = x;
        }
        *(float4*)&C[(size_t)r * ldc + c] = *(float4*)vv;
    }
}

// ---------------- small prep kernels ----------------
__global__ void prep_hprev(const float* __restrict__ lstm_h, const float* __restrict__ masks,
                           float* __restrict__ hprev)
{
    int i = blockIdx.x * 256 + threadIdx.x;
    hprev[i] = lstm_h[i] * masks[i >> 7];
}

__global__ void lstm_pointwise(const float* __restrict__ gates,
                               const float* __restrict__ bih, const float* __restrict__ bhh,
                               const float* __restrict__ lstm_c, const float* __restrict__ masks,
                               float* __restrict__ h,
                               float* __restrict__ out_h, float* __restrict__ out_c)
{
    int idx = blockIdx.x * 256 + threadIdx.x;
    int r = idx >> 7, c = idx & 127;
    const float* g = gates + (size_t)r * G4;
    float gi = g[c]        + bih[c]        + bhh[c];
    float gf = g[128 + c]  + bih[128 + c]  + bhh[128 + c];
    float gg = g[256 + c]  + bih[256 + c]  + bhh[256 + c];
    float go = g[384 + c]  + bih[384 + c]  + bhh[384 + c];
    float cprev = lstm_c[idx] * masks[r];
    float cn = sigf(gf) * cprev + sigf(gi) * tanhf(gg);
    float hn = sigf(go) * tanhf(cn);
    h[idx] = hn;
    out_h[idx] = hn;
    out_c[idx] = cn;
}

// ---------------- persistent bidirectional GRU scan (MFMA, weights-stationary) --------
// grid: 256 blocks (128 fwd + 128 bwd), 512 threads = 8 waves, 32 rows/block.
// Wave w owns h-columns [w*16, w*16+16) for all 3 gates (col-tiles {w, 8+w, 16+w}).
// Whh stays in registers as split-f16 fragments: W ~= Whi + Wlo/1024;
// acc = accA(hi*hi) + accB(hi*lo + lo*hi)/1024  (lo*lo term ~2^-22 rel, dropped).
__global__ __launch_bounds__(512, 2)
void gru_scan(const float* __restrict__ WhhF, const float* __restrict__ WhhB,
              const float* __restrict__ bhhF, const float* __restrict__ bhhB,
              const float* __restrict__ Uf, const float* __restrict__ Vf,
              const float* __restrict__ Ub, const float* __restrict__ Vb,
              const float* __restrict__ Whard,
              float* __restrict__ partF, float* __restrict__ partB)
{
    __shared__ __align__(16) unsigned short hshHi[32][LDSW];
    __shared__ __align__(16) unsigned short hshLo[32][LDSW];
    __shared__ float predsh[8][32][2];

    const int t = threadIdx.x;
    const int dir = blockIdx.x >> 7;
    const int blk = blockIdx.x & 127;
    const int r0 = blk * 32;
    const int bbx = r0 >> 6;
    const int n0 = r0 & 63;
    const int w  = t >> 6;        // wave 0..7
    const int l  = t & 63;        // lane
    const int li = l & 15;
    const int lg = l >> 4;        // 0..3
    const int cl = w * 16 + li;   // owned h column 0..127

    const float* Whh = dir ? WhhB : WhhF;
    const float* bhh = dir ? bhhB : bhhF;
    const float* U   = dir ? Ub   : Uf;
    const float* V   = dir ? Vb   : Vf;
    float* part      = dir ? partB : partF;

    // stationary weight fragments: B[k][n] = Whh[n][k]; lane: n = cl, k = kt*32 + lg*8 + j
    f16x8 Bhi[3][4], Blo[3][4];
    #pragma unroll
    for (int g = 0; g < 3; ++g)
        #pragma unroll
        for (int kt = 0; kt < 4; ++kt) {
            const float* src = Whh + (size_t)(g * 128 + cl) * 128 + kt * 32 + lg * 8;
            #pragma unroll
            for (int j = 0; j < 8; ++j) {
                float wv = src[j];
                _Float16 hi = (_Float16)wv;
                _Float16 lo = (_Float16)((wv - (float)hi) * 1024.0f);
                Bhi[g][kt][j] = hi;
                Blo[g][kt][j] = lo;
            }
        }

    const float bh_r = bhh[cl];
    const float bh_z = bhh[128 + cl];
    const float bh_n = bhh[256 + cl];
    const float wh0  = Whard[dir * 128 + cl];
    const float wh1  = Whard[256 + dir * 128 + cl];

    for (int i = t; i < 32 * LDSW; i += 512) {
        (&hshHi[0][0])[i] = 0;
        (&hshLo[0][0])[i] = 0;
    }
    float hreg[8] = {0.f,0.f,0.f,0.f,0.f,0.f,0.f,0.f};
    __syncthreads();

    for (int s = 0; s < NM; ++s) {
        const int tt = dir ? (NM - 1 - s) : s;

        f32x4 accA[3][2], accB[3][2];
        #pragma unroll
        for (int g = 0; g < 3; ++g)
            #pragma unroll
            for (int rt = 0; rt < 2; ++rt) {
                accA[g][rt] = (f32x4){0.f,0.f,0.f,0.f};
                accB[g][rt] = (f32x4){0.f,0.f,0.f,0.f};
            }

        #pragma unroll
        for (int kt = 0; kt < 4; ++kt) {
            f16x8 Ahi[2], Alo[2];
            const int koff = kt * 32 + lg * 8;
            #pragma unroll
            for (int rt = 0; rt < 2; ++rt) {
                const int arow = rt * 16 + li;      // A: row = lane&15
                Ahi[rt] = *(const f16x8*)&hshHi[arow][koff];
                Alo[rt] = *(const f16x8*)&hshLo[arow][koff];
            }
            #pragma unroll
            for (int g = 0; g < 3; ++g)
                #pragma unroll
                for (int rt = 0; rt < 2; ++rt) {
                    accA[g][rt] = __builtin_amdgcn_mfma_f32_16x16x32_f16(Ahi[rt], Bhi[g][kt], accA[g][rt], 0, 0, 0);
                    accB[g][rt] = __builtin_amdgcn_mfma_f32_16x16x32_f16(Alo[rt], Bhi[g][kt], accB[g][rt], 0, 0, 0);
                    accB[g][rt] = __builtin_amdgcn_mfma_f32_16x16x32_f16(Ahi[rt], Blo[g][kt], accB[g][rt], 0, 0, 0);
                }
        }

        // epilogue: C-layout col = lane&15 (= cl), row = rt*16 + lg*4 + reg
        float hnew[8];
        #pragma unroll
        for (int rt = 0; rt < 2; ++rt) {
            #pragma unroll
            for (int rg = 0; rg < 4; ++rg) {
                const int row = rt * 16 + lg * 4 + rg;
                const int R = r0 + row;
                const int n = n0 + row;
                const int vrow = (bbx << 6) + tt + (tt >= n ? 1 : 0);
                const float* Ur = U + (size_t)R * G3;
                const float* Vr = V + (size_t)vrow * G3;
                const float gr = accA[0][rt][rg] + accB[0][rt][rg] * 9.765625e-4f + bh_r;
                const float gz = accA[1][rt][rg] + accB[1][rt][rg] * 9.765625e-4f + bh_z;
                const float gn = accA[2][rt][rg] + accB[2][rt][rg] * 9.765625e-4f + bh_n;
                const float rr  = sigf(Ur[cl]       + Vr[cl]       + gr);
                const float zz  = sigf(Ur[128 + cl] + Vr[128 + cl] + gz);
                const float nn2 = tanhf(Ur[256 + cl] + Vr[256 + cl] + rr * gn);
                const float hn  = (1.0f - zz) * nn2 + zz * hreg[rt * 4 + rg];
                hreg[rt * 4 + rg] = hn;
                hnew[rt * 4 + rg] = hn;
            }
        }

        __syncthreads();   // B1: all A-reads of this step done; prev part-store reads done

        #pragma unroll
        for (int rt = 0; rt < 2; ++rt)
            #pragma unroll
            for (int rg = 0; rg < 4; ++rg) {
                const int row = rt * 16 + lg * 4 + rg;
                const float hn = hnew[rt * 4 + rg];
                _Float16 hi = (_Float16)hn;
                _Float16 lo = (_Float16)((hn - (float)hi) * 1024.0f);
                hshHi[row][cl] = h2u(hi);
                hshLo[row][cl] = h2u(lo);
            }

        // fused W_hard partial logits: reduce over this wave's 16 columns
        #pragma unroll
        for (int idx = 0; idx < 8; ++idx) {
            float p0 = hnew[idx] * wh0;
            float p1 = hnew[idx] * wh1;
            #pragma unroll
            for (int d = 1; d < 16; d <<= 1) {
                p0 += __shfl_xor(p0, d);
                p1 += __shfl_xor(p1, d);
            }
            if (li == 0) {
                const int row = (idx >> 2) * 16 + lg * 4 + (idx & 3);
                predsh[w][row][0] = p0;
                predsh[w][row][1] = p1;
            }
        }

        __syncthreads();   // B2: h + pred visible

        if (t < 64) {
            const int prow = t >> 1, c = t & 1;
            float ssum = 0.0f;
            #pragma unroll
            for (int ww = 0; ww < 8; ++ww) ssum += predsh[ww][prow][c];
            part[((size_t)(r0 + prow) * NM + tt) * 2 + c] = ssum;
        }
    }
}

// ---------------- hard gate + soft attention + action head ----------------
__global__ __launch_bounds__(128)
void attn_final(const float* __restrict__ h, const float* __restrict__ q,
                const float* __restrict__ kk,
                const float* __restrict__ partF, const float* __restrict__ partB,
                const float* __restrict__ bhard, const float* __restrict__ gum,
                const float* __restrict__ Wact, const float* __restrict__ bact,
                float* __restrict__ out_act, float* __restrict__ out_alp)
{
    const int r = blockIdx.x;
    const int bbx = r >> 6, n = r & 63;
    const int t = threadIdx.x;
    __shared__ float qsh[HH], wsh[NM], shh[HH], shx[HH];
    if (t < HH) { qsh[t] = q[(size_t)r * HH + t]; shh[t] = h[(size_t)r * HH + t]; }
    __syncthreads();
    if (t < 64) {
        float sc = -INFINITY;
        float hardv = 0.0f;
        if (t < NM) {
            const int idxm = t + (t >= n ? 1 : 0);
            const float4* kr = (const float4*)(kk + (size_t)((bbx << 6) + idxm) * HH);
            float s = 0.0f;
            #pragma unroll
            for (int j4 = 0; j4 < 32; ++j4) {
                float4 kv = kr[j4];
                float4 qv = *(const float4*)&qsh[j4 * 4];
                s += kv.x * qv.x + kv.y * qv.y + kv.z * qv.z + kv.w * qv.w;
            }
            sc = s * 0.088388347648318447f;   // 1/sqrt(128)
            const float2 pf = *(const float2*)(partF + ((size_t)r * NM + t) * 2);
            const float2 pb = *(const float2*)(partB + ((size_t)r * NM + t) * 2);
            const float2 gv = *(const float2*)(gum + ((size_t)r * NM + t) * 2);
            const float l0 = pf.x + pb.x + bhard[0] + gv.x;
            const float l1 = pf.y + pb.y + bhard[1] + gv.y;
            hardv = (l1 > l0) ? 1.0f : 0.0f;
        }
        float mx = sc;
        #pragma unroll
        for (int d = 32; d; d >>= 1) mx = fmaxf(mx, __shfl_xor(mx, d, 64));
        const float e = (t < NM) ? expf(sc - mx) : 0.0f;
        float sum = e;
        #pragma unroll
        for (int d = 32; d; d >>= 1) sum += __shfl_xor(sum, d, 64);
        if (t < NM) wsh[t] = hardv * e / sum;
    }
    __syncthreads();
    {
        const int j = t;
        float x = 0.0f;
        for (int m = 0; m < NM; ++m) {
            const int idxm = m + (m >= n ? 1 : 0);
            x = fmaf(wsh[m], h[(size_t)((bbx << 6) + idxm) * HH + j], x);
        }
        shx[j] = x;
    }
    __syncthreads();
    if (t < 16) {
        const float* wa = Wact + (size_t)t * 256;
        float acc = bact[t];
        #pragma unroll
        for (int j4 = 0; j4 < 32; ++j4) {
            float4 w1 = *(const float4*)&wa[j4 * 4];
            float4 hv = *(const float4*)&shh[j4 * 4];
            float4 w2 = *(const float4*)&wa[128 + j4 * 4];
            float4 xv = *(const float4*)&shx[j4 * 4];
            acc += w1.x * hv.x + w1.y * hv.y + w1.z * hv.z + w1.w * hv.w
                 + w2.x * xv.x + w2.y * xv.y + w2.z * xv.z + w2.w * xv.w;
        }
        float mx = acc; int am = t;
        #pragma unroll
        for (int d = 8; d; d >>= 1) {
            const float om = __shfl_xor(mx, d, 16);
            const int   oa = __shfl_xor(am, d, 16);
            if (om > mx || (om == mx && oa < am)) { mx = om; am = oa; }
        }
        const float e = expf(acc - mx);
        float sum = e;
        #pragma unroll
        for (int d = 8; d; d >>= 1) sum += __shfl_xor(sum, d, 16);
        if (t == 0) {
            out_act[r] = (float)am;
            out_alp[r] = -logf(sum);
        }
    }
}

// ---------------- launch ----------------
extern "C" void kernel_launch(void* const* d_in, const int* in_sizes, int n_in,
                              void* d_out, int out_size, void* d_ws, size_t ws_size,
                              hipStream_t stream)
{
    const float* obs    = (const float*)d_in[0];
    const float* lstm_h = (const float*)d_in[1];
    const float* lstm_c = (const float*)d_in[2];
    const float* masks  = (const float*)d_in[3];
    const float* W_enc  = (const float*)d_in[4];
    const float* b_enc  = (const float*)d_in[5];
    const float* lWih   = (const float*)d_in[6];
    const float* lWhh   = (const float*)d_in[7];
    const float* lbih   = (const float*)d_in[8];
    const float* lbhh   = (const float*)d_in[9];
    const float* gWihf  = (const float*)d_in[10];
    const float* gWhhf  = (const float*)d_in[11];
    const float* gbihf  = (const float*)d_in[12];
    const float* gbhhf  = (const float*)d_in[13];
    const float* gWihb  = (const float*)d_in[14];
    const float* gWhhb  = (const float*)d_in[15];
    const float* gbihb  = (const float*)d_in[16];
    const float* gbhhb  = (const float*)d_in[17];
    const float* Whard  = (const float*)d_in[18];
    const float* bhard  = (const float*)d_in[19];
    const float* Wq     = (const float*)d_in[20];
    const float* Wk     = (const float*)d_in[21];
    const float* Wact   = (const float*)d_in[22];
    const float* bact   = (const float*)d_in[23];
    const float* gum    = (const float*)d_in[24];

    float* W = (float*)d_ws;
    float* h     = W; W += (size_t)BN_ * HH;
    float* hprev = W; W += (size_t)BN_ * HH;
    float* henc  = W; W += (size_t)BN_ * HH;
    float* gates = W; W += (size_t)BN_ * G4;
    float* Uf    = W; W += (size_t)BN_ * G3;
    float* Vf    = W; W += (size_t)BN_ * G3;
    float* Ub    = W; W += (size_t)BN_ * G3;
    float* Vb    = W; W += (size_t)BN_ * G3;
    float* partF = W; W += (size_t)BN_ * NM * 2;
    float* partB = W; W += (size_t)BN_ * NM * 2;
    float* qq    = W; W += (size_t)BN_ * HH;
    float* kk    = W; W += (size_t)BN_ * HH;

    float* out_f   = (float*)d_out;
    float* out_act = out_f;                       // 4096
    float* out_alp = out_act + BN_;               // 4096
    float* out_h   = out_alp + BN_;               // 4096*128
    float* out_c   = out_h + (size_t)BN_ * HH;    // 4096*128

    prep_hprev<<<BN_ * HH / 256, 256, 0, stream>>>(lstm_h, masks, hprev);
    gemm_tn<false, true, true><<<dim3(HH / 64, BN_ / 64), 256, 0, stream>>>(
        obs, OBS_, W_enc, OBS_, nullptr, 0, nullptr, 0, b_enc, henc, HH, OBS_);
    gemm_tn<true, false, false><<<dim3(G4 / 64, BN_ / 64), 256, 0, stream>>>(
        henc, HH, lWih, HH, hprev, HH, lWhh, HH, nullptr, gates, G4, HH);
    lstm_pointwise<<<BN_ * HH / 256, 256, 0, stream>>>(gates, lbih, lbhh, lstm_c, masks,
                                                       h, out_h, out_c);
    gemm_tn<false, false, true><<<dim3(G3 / 64, BN_ / 64), 256, 0, stream>>>(
        h, HH, gWihf, 2 * HH, nullptr, 0, nullptr, 0, gbihf, Uf, G3, HH);
    gemm_tn<false, false, false><<<dim3(G3 / 64, BN_ / 64), 256, 0, stream>>>(
        h, HH, gWihf + HH, 2 * HH, nullptr, 0, nullptr, 0, nullptr, Vf, G3, HH);
    gemm_tn<false, false, true><<<dim3(G3 / 64, BN_ / 64), 256, 0, stream>>>(
        h, HH, gWihb, 2 * HH, nullptr, 0, nullptr, 0, gbihb, Ub, G3, HH);
    gemm_tn<false, false, false><<<dim3(G3 / 64, BN_ / 64), 256, 0, stream>>>(
        h, HH, gWihb + HH, 2 * HH, nullptr, 0, nullptr, 0, nullptr, Vb, G3, HH);
    gemm_tn<false, false, false><<<dim3(HH / 64, BN_ / 64), 256, 0, stream>>>(
        h, HH, Wq, HH, nullptr, 0, nullptr, 0, nullptr, qq, HH, HH);
    gemm_tn<false, false, false><<<dim3(HH / 64, BN_ / 64), 256, 0, stream>>>(
        h, HH, Wk, HH, nullptr, 0, nullptr, 0, nullptr, kk, HH, HH);
    gru_scan<<<256, 512, 0, stream>>>(gWhhf, gWhhb, gbhhf, gbhhb, Uf, Vf, Ub, Vb,
                                      Whard, partF, partB);
    attn_final<<<BN_, 128, 0, stream>>>(h, qq, kk, partF, partB, bhard, gum,
                                        Wact, bact, out_act, out_alp);
}

// Round 6
// 482.930 us; speedup vs baseline: 2.6053x; 1.1111x over previous
//
#include <hip/hip_runtime.h>
#include <hip/hip_bf16.h>
#include <math.h>

#define BB   64
#define NN   64
#define HH   128
#define OBS_ 128
#define AA   16
#define BN_  4096
#define NM   63
#define G3   384
#define G4   512
#define LDSW 136   // ushort stride: 272B rows -> dword-bank stride 4 -> 2-way (free) on b128 reads

typedef _Float16 f16x8 __attribute__((ext_vector_type(8)));
typedef float    f32x4 __attribute__((ext_vector_type(4)));

__device__ __forceinline__ float sigf(float x) { return 1.0f / (1.0f + expf(-x)); }

__device__ __forceinline__ unsigned short h2u(_Float16 h) {
    union { _Float16 f; unsigned short u; } cv; cv.f = h; return cv.u;
}

// ---------------- generic C = A@B^T (+ A2@B2^T) (+bias) (+relu), tile 64x64, K=128 ----
template<bool DUAL, bool RELU, bool BIAS>
__global__ __launch_bounds__(256)
void gemm_tn(const float* __restrict__ A, int lda,
             const float* __restrict__ B, int ldb,
             const float* __restrict__ A2, int lda2,
             const float* __restrict__ B2, int ldb2,
             const float* __restrict__ bias,
             float* __restrict__ C, int ldc, int K)
{
    __shared__ float As[32][68];
    __shared__ float Bs[32][68];
    const int t = threadIdx.x;
    const int tx = t & 15, ty = t >> 4;
    const int row0 = blockIdx.y * 64, col0 = blockIdx.x * 64;
    const int lm = t >> 2;           // 0..63
    const int lk = (t & 3) * 8;      // 0,8,16,24
    float acc[4][4] = {};
    const int npass = DUAL ? 2 : 1;
    for (int pass = 0; pass < npass; ++pass) {
        const float* Ap = pass ? A2 : A; const int ldap = pass ? lda2 : lda;
        const float* Bp = pass ? B2 : B; const int ldbp = pass ? ldb2 : ldb;
        for (int k0 = 0; k0 < K; k0 += 32) {
            __syncthreads();
            {
                const float* srcA = Ap + (size_t)(row0 + lm) * ldap + k0 + lk;
                float4 a0 = *(const float4*)(srcA);
                float4 a1 = *(const float4*)(srcA + 4);
                As[lk + 0][lm] = a0.x; As[lk + 1][lm] = a0.y; As[lk + 2][lm] = a0.z; As[lk + 3][lm] = a0.w;
                As[lk + 4][lm] = a1.x; As[lk + 5][lm] = a1.y; As[lk + 6][lm] = a1.z; As[lk + 7][lm] = a1.w;
                const float* srcB = Bp + (size_t)(col0 + lm) * ldbp + k0 + lk;
                float4 b0 = *(const float4*)(srcB);
                float4 b1 = *(const float4*)(srcB + 4);
                Bs[lk + 0][lm] = b0.x; Bs[lk + 1][lm] = b0.y; Bs[lk + 2][lm] = b0.z; Bs[lk + 3][lm] = b0.w;
                Bs[lk + 4][lm] = b1.x; Bs[lk + 5][lm] = b1.y; Bs[lk + 6][lm] = b1.z; Bs[lk + 7][lm] = b1.w;
            }
            __syncthreads();
            #pragma unroll
            for (int k = 0; k < 32; ++k) {
                float av[4], bv[4];
                *(float4*)av = *(const float4*)&As[k][ty * 4];
                *(float4*)bv = *(const float4*)&Bs[k][tx * 4];
                #pragma unroll
                for (int i = 0; i < 4; ++i)
                    #pragma unroll
                    for (int j = 0; j < 4; ++j)
                        acc[i][j] = fmaf(av[i], bv[j], acc[i][j]);
            }
        }
    }
    #pragma unroll
    for (int i = 0; i < 4; ++i) {
        const int r = row0 + ty * 4 + i;
        const int c = col0 + tx * 4;
        float vv[4];
        #pragma unroll
        for (int j = 0; j < 4; ++j) {
            float x = acc[i][j];
            if (BIAS) x += bias[c + j];
            if (RELU) x = fmaxf(x, 0.0f);
            vv[j] = x;
        }
        *(float4*)&C[(size_t)r * ldc + c] = *(float4*)vv;
    }
}

// ---------------- small prep kernels ----------------
__global__ void prep_hprev(const float* __restrict__ lstm_h, const float* __restrict__ masks,
                           float* __restrict__ hprev)
{
    int i = blockIdx.x * 256 + threadIdx.x;
    hprev[i] = lstm_h[i] * masks[i >> 7];
}

__global__ void lstm_pointwise(const float* __restrict__ gates,
                               const float* __restrict__ bih, const float* __restrict__ bhh,
                               const float* __restrict__ lstm_c, const float* __restrict__ masks,
                               float* __restrict__ h,
                               float* __restrict__ out_h, float* __restrict__ out_c)
{
    int idx = blockIdx.x * 256 + threadIdx.x;
    int r = idx >> 7, c = idx & 127;
    const float* g = gates + (size_t)r * G4;
    float gi = g[c]        + bih[c]        + bhh[c];
    float gf = g[128 + c]  + bih[128 + c]  + bhh[128 + c];
    float gg = g[256 + c]  + bih[256 + c]  + bhh[256 + c];
    float go = g[384 + c]  + bih[384 + c]  + bhh[384 + c];
    float cprev = lstm_c[idx] * masks[r];
    float cn = sigf(gf) * cprev + sigf(gi) * tanhf(gg);
    float hn = sigf(go) * tanhf(cn);
    h[idx] = hn;
    out_h[idx] = hn;
    out_c[idx] = cn;
}

// ---------------- persistent bidirectional GRU scan (MFMA, weights-stationary) --------
// grid: 256 blocks (128 fwd + 128 bwd), 512 threads = 8 waves, 32 rows/block.
// Wave w owns h-columns [w*16, w*16+16) for all 3 gates.
// Whh stationary in registers (split-f16 hi + lo/1024, 3-MFMA product).
// U (step-invariant) preloaded to 24 registers/thread.
// V: only rows {tt, tt+1} are read per step -> 6 regs, prefetched one step ahead.
__global__ __launch_bounds__(512, 2)
void gru_scan(const float* __restrict__ WhhF, const float* __restrict__ WhhB,
              const float* __restrict__ bhhF, const float* __restrict__ bhhB,
              const float* __restrict__ Uf, const float* __restrict__ Vf,
              const float* __restrict__ Ub, const float* __restrict__ Vb,
              const float* __restrict__ Whard,
              float* __restrict__ partF, float* __restrict__ partB)
{
    __shared__ __align__(16) unsigned short hshHi[32][LDSW];
    __shared__ __align__(16) unsigned short hshLo[32][LDSW];
    __shared__ float predsh[8][32][2];

    const int t = threadIdx.x;
    const int dir = blockIdx.x >> 7;
    const int blk = blockIdx.x & 127;
    const int r0 = blk * 32;
    const int bbx = r0 >> 6;
    const int n0 = r0 & 63;
    const int w  = t >> 6;        // wave 0..7
    const int l  = t & 63;        // lane
    const int li = l & 15;
    const int lg = l >> 4;        // 0..3
    const int cl = w * 16 + li;   // owned h column 0..127

    const float* Whh = dir ? WhhB : WhhF;
    const float* bhh = dir ? bhhB : bhhF;
    const float* U   = dir ? Ub   : Uf;
    const float* V   = dir ? Vb   : Vf;
    float* part      = dir ? partB : partF;

    // stationary weight fragments: B[k][n] = Whh[n][k]; lane: n = cl, k = kt*32 + lg*8 + j
    f16x8 Bhi[3][4], Blo[3][4];
    #pragma unroll
    for (int g = 0; g < 3; ++g)
        #pragma unroll
        for (int kt = 0; kt < 4; ++kt) {
            const float* src = Whh + (size_t)(g * 128 + cl) * 128 + kt * 32 + lg * 8;
            #pragma unroll
            for (int j = 0; j < 8; ++j) {
                float wv = src[j];
                _Float16 hi = (_Float16)wv;
                _Float16 lo = (_Float16)((wv - (float)hi) * 1024.0f);
                Bhi[g][kt][j] = hi;
                Blo[g][kt][j] = lo;
            }
        }

    const float bh_r = bhh[cl];
    const float bh_z = bhh[128 + cl];
    const float bh_n = bhh[256 + cl];
    const float wh0  = Whard[dir * 128 + cl];
    const float wh1  = Whard[256 + dir * 128 + cl];

    // step-invariant U gate values for this thread's 8 (row, col=cl) output slots
    float u_r[8], u_z[8], u_n[8];
    #pragma unroll
    for (int rt = 0; rt < 2; ++rt)
        #pragma unroll
        for (int rg = 0; rg < 4; ++rg) {
            const int idx = rt * 4 + rg;
            const int R = r0 + rt * 16 + lg * 4 + rg;
            const float* Ur = U + (size_t)R * G3;
            u_r[idx] = Ur[cl];
            u_z[idx] = Ur[128 + cl];
            u_n[idx] = Ur[256 + cl];
        }

    // V pipeline: rows {tt, tt+1} of this batch; prefetch regs for current step
    const int vbase = bbx << 6;
    float v0r, v0z, v0n, v1r, v1z, v1n;
    {
        const int tt0 = dir ? (NM - 1) : 0;
        const float* Vr0 = V + (size_t)(vbase + tt0) * G3;
        const float* Vr1 = V + (size_t)(vbase + tt0 + 1) * G3;
        v0r = Vr0[cl]; v0z = Vr0[128 + cl]; v0n = Vr0[256 + cl];
        v1r = Vr1[cl]; v1z = Vr1[128 + cl]; v1n = Vr1[256 + cl];
    }

    for (int i = t; i < 32 * LDSW; i += 512) {
        (&hshHi[0][0])[i] = 0;
        (&hshLo[0][0])[i] = 0;
    }
    float hreg[8] = {0.f,0.f,0.f,0.f,0.f,0.f,0.f,0.f};
    __syncthreads();

    for (int s = 0; s < NM; ++s) {
        const int tt = dir ? (NM - 1 - s) : s;

        // issue next-step V prefetch (latency hides under MFMA)
        float p0r, p0z, p0n, p1r, p1z, p1n;
        {
            const int sn = (s + 1 < NM) ? s + 1 : s;
            const int ttn = dir ? (NM - 1 - sn) : sn;
            const float* Vr0 = V + (size_t)(vbase + ttn) * G3;
            const float* Vr1 = V + (size_t)(vbase + ttn + 1) * G3;
            p0r = Vr0[cl]; p0z = Vr0[128 + cl]; p0n = Vr0[256 + cl];
            p1r = Vr1[cl]; p1z = Vr1[128 + cl]; p1n = Vr1[256 + cl];
        }

        f32x4 accA[3][2], accB[3][2];
        #pragma unroll
        for (int g = 0; g < 3; ++g)
            #pragma unroll
            for (int rt = 0; rt < 2; ++rt) {
                accA[g][rt] = (f32x4){0.f,0.f,0.f,0.f};
                accB[g][rt] = (f32x4){0.f,0.f,0.f,0.f};
            }

        #pragma unroll
        for (int kt = 0; kt < 4; ++kt) {
            f16x8 Ahi[2], Alo[2];
            const int koff = kt * 32 + lg * 8;
            #pragma unroll
            for (int rt = 0; rt < 2; ++rt) {
                const int arow = rt * 16 + li;      // A: row = lane&15
                Ahi[rt] = *(const f16x8*)&hshHi[arow][koff];
                Alo[rt] = *(const f16x8*)&hshLo[arow][koff];
            }
            #pragma unroll
            for (int g = 0; g < 3; ++g)
                #pragma unroll
                for (int rt = 0; rt < 2; ++rt) {
                    accA[g][rt] = __builtin_amdgcn_mfma_f32_16x16x32_f16(Ahi[rt], Bhi[g][kt], accA[g][rt], 0, 0, 0);
                    accB[g][rt] = __builtin_amdgcn_mfma_f32_16x16x32_f16(Alo[rt], Bhi[g][kt], accB[g][rt], 0, 0, 0);
                    accB[g][rt] = __builtin_amdgcn_mfma_f32_16x16x32_f16(Ahi[rt], Blo[g][kt], accB[g][rt], 0, 0, 0);
                }
        }

        // epilogue: C-layout col = lane&15 (= cl), row = rt*16 + lg*4 + reg
        #pragma unroll
        for (int rt = 0; rt < 2; ++rt) {
            #pragma unroll
            for (int rg = 0; rg < 4; ++rg) {
                const int idx = rt * 4 + rg;
                const int row = rt * 16 + lg * 4 + rg;
                const int n = n0 + row;
                const bool up = (tt >= n);
                const float vr_ = up ? v1r : v0r;
                const float vz_ = up ? v1z : v0z;
                const float vn_ = up ? v1n : v0n;
                const float gr = accA[0][rt][rg] + accB[0][rt][rg] * 9.765625e-4f + bh_r;
                const float gz = accA[1][rt][rg] + accB[1][rt][rg] * 9.765625e-4f + bh_z;
                const float gn = accA[2][rt][rg] + accB[2][rt][rg] * 9.765625e-4f + bh_n;
                const float rr  = sigf(u_r[idx] + vr_ + gr);
                const float zz  = sigf(u_z[idx] + vz_ + gz);
                const float nn2 = tanhf(u_n[idx] + vn_ + rr * gn);
                hreg[idx] = (1.0f - zz) * nn2 + zz * hreg[idx];
            }
        }

        // rotate V pipeline
        v0r = p0r; v0z = p0z; v0n = p0n;
        v1r = p1r; v1z = p1z; v1n = p1n;

        __syncthreads();   // B1: all A-reads of this step done; prev part-store reads done

        #pragma unroll
        for (int rt = 0; rt < 2; ++rt)
            #pragma unroll
            for (int rg = 0; rg < 4; ++rg) {
                const int row = rt * 16 + lg * 4 + rg;
                const float hn = hreg[rt * 4 + rg];
                _Float16 hi = (_Float16)hn;
                _Float16 lo = (_Float16)((hn - (float)hi) * 1024.0f);
                hshHi[row][cl] = h2u(hi);
                hshLo[row][cl] = h2u(lo);
            }

        // fused W_hard partial logits: reduce over this wave's 16 columns
        #pragma unroll
        for (int idx = 0; idx < 8; ++idx) {
            float p0 = hreg[idx] * wh0;
            float p1 = hreg[idx] * wh1;
            #pragma unroll
            for (int d = 1; d < 16; d <<= 1) {
                p0 += __shfl_xor(p0, d);
                p1 += __shfl_xor(p1, d);
            }
            if (li == 0) {
                const int row = (idx >> 2) * 16 + lg * 4 + (idx & 3);
                predsh[w][row][0] = p0;
                predsh[w][row][1] = p1;
            }
        }

        __syncthreads();   // B2: h + pred visible

        if (t < 64) {
            const int prow = t >> 1, c = t & 1;
            float ssum = 0.0f;
            #pragma unroll
            for (int ww = 0; ww < 8; ++ww) ssum += predsh[ww][prow][c];
            part[((size_t)(r0 + prow) * NM + tt) * 2 + c] = ssum;
        }
    }
}

// ---------------- hard gate + soft attention + action head ----------------
__global__ __launch_bounds__(128)
void attn_final(const float* __restrict__ h, const float* __restrict__ q,
                const float* __restrict__ kk,
                const float* __restrict__ partF, const float* __restrict__ partB,
                const float* __restrict__ bhard, const float* __restrict__ gum,
                const float* __restrict__ Wact, const float* __restrict__ bact,
                float* __restrict__ out_act, float* __restrict__ out_alp)
{
    const int r = blockIdx.x;
    const int bbx = r >> 6, n = r & 63;
    const int t = threadIdx.x;
    __shared__ float qsh[HH], wsh[NM], shh[HH], shx[HH];
    if (t < HH) { qsh[t] = q[(size_t)r * HH + t]; shh[t] = h[(size_t)r * HH + t]; }
    __syncthreads();
    if (t < 64) {
        float sc = -INFINITY;
        float hardv = 0.0f;
        if (t < NM) {
            const int idxm = t + (t >= n ? 1 : 0);
            const float4* kr = (const float4*)(kk + (size_t)((bbx << 6) + idxm) * HH);
            float s = 0.0f;
            #pragma unroll
            for (int j4 = 0; j4 < 32; ++j4) {
                float4 kv = kr[j4];
                float4 qv = *(const float4*)&qsh[j4 * 4];
                s += kv.x * qv.x + kv.y * qv.y + kv.z * qv.z + kv.w * qv.w;
            }
            sc = s * 0.088388347648318447f;   // 1/sqrt(128)
            const float2 pf = *(const float2*)(partF + ((size_t)r * NM + t) * 2);
            const float2 pb = *(const float2*)(partB + ((size_t)r * NM + t) * 2);
            const float2 gv = *(const float2*)(gum + ((size_t)r * NM + t) * 2);
            const float l0 = pf.x + pb.x + bhard[0] + gv.x;
            const float l1 = pf.y + pb.y + bhard[1] + gv.y;
            hardv = (l1 > l0) ? 1.0f : 0.0f;
        }
        float mx = sc;
        #pragma unroll
        for (int d = 32; d; d >>= 1) mx = fmaxf(mx, __shfl_xor(mx, d, 64));
        const float e = (t < NM) ? expf(sc - mx) : 0.0f;
        float sum = e;
        #pragma unroll
        for (int d = 32; d; d >>= 1) sum += __shfl_xor(sum, d, 64);
        if (t < NM) wsh[t] = hardv * e / sum;
    }
    __syncthreads();
    {
        const int j = t;
        float x = 0.0f;
        for (int m = 0; m < NM; ++m) {
            const int idxm = m + (m >= n ? 1 : 0);
            x = fmaf(wsh[m], h[(size_t)((bbx << 6) + idxm) * HH + j], x);
        }
        shx[j] = x;
    }
    __syncthreads();
    if (t < 16) {
        const float* wa = Wact + (size_t)t * 256;
        float acc = bact[t];
        #pragma unroll
        for (int j4 = 0; j4 < 32; ++j4) {
            float4 w1 = *(const float4*)&wa[j4 * 4];
            float4 hv = *(const float4*)&shh[j4 * 4];
            float4 w2 = *(const float4*)&wa[128 + j4 * 4];
            float4 xv = *(const float4*)&shx[j4 * 4];
            acc += w1.x * hv.x + w1.y * hv.y + w1.z * hv.z + w1.w * hv.w
                 + w2.x * xv.x + w2.y * xv.y + w2.z * xv.z + w2.w * xv.w;
        }
        float mx = acc; int am = t;
        #pragma unroll
        for (int d = 8; d; d >>= 1) {
            const float om = __shfl_xor(mx, d, 16);
            const int   oa = __shfl_xor(am, d, 16);
            if (om > mx || (om == mx && oa < am)) { mx = om; am = oa; }
        }
        const float e = expf(acc - mx);
        float sum = e;
        #pragma unroll
        for (int d = 8; d; d >>= 1) sum += __shfl_xor(sum, d, 16);
        if (t == 0) {
            out_act[r] = (float)am;
            out_alp[r] = -logf(sum);
        }
    }
}

// ---------------- launch ----------------
extern "C" void kernel_launch(void* const* d_in, const int* in_sizes, int n_in,
                              void* d_out, int out_size, void* d_ws, size_t ws_size,
                              hipStream_t stream)
{
    const float* obs    = (const float*)d_in[0];
    const float* lstm_h = (const float*)d_in[1];
    const float* lstm_c = (const float*)d_in[2];
    const float* masks  = (const float*)d_in[3];
    const float* W_enc  = (const float*)d_in[4];
    const float* b_enc  = (const float*)d_in[5];
    const float* lWih   = (const float*)d_in[6];
    const float* lWhh   = (const float*)d_in[7];
    const float* lbih   = (const float*)d_in[8];
    const float* lbhh   = (const float*)d_in[9];
    const float* gWihf  = (const float*)d_in[10];
    const float* gWhhf  = (const float*)d_in[11];
    const float* gbihf  = (const float*)d_in[12];
    const float* gbhhf  = (const float*)d_in[13];
    const float* gWihb  = (const float*)d_in[14];
    const float* gWhhb  = (const float*)d_in[15];
    const float* gbihb  = (const float*)d_in[16];
    const float* gbhhb  = (const float*)d_in[17];
    const float* Whard  = (const float*)d_in[18];
    const float* bhard  = (const float*)d_in[19];
    const float* Wq     = (const float*)d_in[20];
    const float* Wk     = (const float*)d_in[21];
    const float* Wact   = (const float*)d_in[22];
    const float* bact   = (const float*)d_in[23];
    const float* gum    = (const float*)d_in[24];

    float* W = (float*)d_ws;
    float* h     = W; W += (size_t)BN_ * HH;
    float* hprev = W; W += (size_t)BN_ * HH;
    float* henc  = W; W += (size_t)BN_ * HH;
    float* gates = W; W += (size_t)BN_ * G4;
    float* Uf    = W; W += (size_t)BN_ * G3;
    float* Vf    = W; W += (size_t)BN_ * G3;
    float* Ub    = W; W += (size_t)BN_ * G3;
    float* Vb    = W; W += (size_t)BN_ * G3;
    float* partF = W; W += (size_t)BN_ * NM * 2;
    float* partB = W; W += (size_t)BN_ * NM * 2;
    float* qq    = W; W += (size_t)BN_ * HH;
    float* kk    = W; W += (size_t)BN_ * HH;

    float* out_f   = (float*)d_out;
    float* out_act = out_f;                       // 4096
    float* out_alp = out_act + BN_;               // 4096
    float* out_h   = out_alp + BN_;               // 4096*128
    float* out_c   = out_h + (size_t)BN_ * HH;    // 4096*128

    prep_hprev<<<BN_ * HH / 256, 256, 0, stream>>>(lstm_h, masks, hprev);
    gemm_tn<false, true, true><<<dim3(HH / 64, BN_ / 64), 256, 0, stream>>>(
        obs, OBS_, W_enc, OBS_, nullptr, 0, nullptr, 0, b_enc, henc, HH, OBS_);
    gemm_tn<true, false, false><<<dim3(G4 / 64, BN_ / 64), 256, 0, stream>>>(
        henc, HH, lWih, HH, hprev, HH, lWhh, HH, nullptr, gates, G4, HH);
    lstm_pointwise<<<BN_ * HH / 256, 256, 0, stream>>>(gates, lbih, lbhh, lstm_c, masks,
                                                       h, out_h, out_c);
    gemm_tn<false, false, true><<<dim3(G3 / 64, BN_ / 64), 256, 0, stream>>>(
        h, HH, gWihf, 2 * HH, nullptr, 0, nullptr, 0, gbihf, Uf, G3, HH);
    gemm_tn<false, false, false><<<dim3(G3 / 64, BN_ / 64), 256, 0, stream>>>(
        h, HH, gWihf + HH, 2 * HH, nullptr, 0, nullptr, 0, nullptr, Vf, G3, HH);
    gemm_tn<false, false, true><<<dim3(G3 / 64, BN_ / 64), 256, 0, stream>>>(
        h, HH, gWihb, 2 * HH, nullptr, 0, nullptr, 0, gbihb, Ub, G3, HH);
    gemm_tn<false, false, false><<<dim3(G3 / 64, BN_ / 64), 256, 0, stream>>>(
        h, HH, gWihb + HH, 2 * HH, nullptr, 0, nullptr, 0, nullptr, Vb, G3, HH);
    gemm_tn<false, false, false><<<dim3(HH / 64, BN_ / 64), 256, 0, stream>>>(
        h, HH, Wq, HH, nullptr, 0, nullptr, 0, nullptr, qq, HH, HH);
    gemm_tn<false, false, false><<<dim3(HH / 64, BN_ / 64), 256, 0, stream>>>(
        h, HH, Wk, HH, nullptr, 0, nullptr, 0, nullptr, kk, HH, HH);
    gru_scan<<<256, 512, 0, stream>>>(gWhhf, gWhhb, gbhhf, gbhhb, Uf, Vf, Ub, Vb,
                                      Whard, partF, partB);
    attn_final<<<BN_, 128, 0, stream>>>(h, qq, kk, partF, partB, bhard, gum,
                                        Wact, bact, out_act, out_alp);
}

// Round 7
// 420.925 us; speedup vs baseline: 2.9891x; 1.1473x over previous
//
#include <hip/hip_runtime.h>
#include <hip/hip_bf16.h>
#include <math.h>

#define BB   64
#define NN   64
#define HH   128
#define OBS_ 128
#define AA   16
#define BN_  4096
#define NM   63
#define G3   384
#define G4   512
#define LDSW 136   // ushorts/row: 68 dw, /4 = 17 odd -> uniform 8-lane bank-group spread on b128 reads

typedef _Float16 f16x8 __attribute__((ext_vector_type(8)));
typedef float    f32x4 __attribute__((ext_vector_type(4)));

__device__ __forceinline__ float sigf(float x) { return 1.0f / (1.0f + expf(-x)); }

// fast device transcendentals (v_exp_f32 / v_rcp_f32, ~2-3 ulp)
__device__ __forceinline__ float fsig(float x) {
    return __builtin_amdgcn_rcpf(1.0f + __builtin_amdgcn_exp2f(-1.4426950408889634f * x));
}
__device__ __forceinline__ float ftanh(float x) {
    return 1.0f - 2.0f * __builtin_amdgcn_rcpf(1.0f + __builtin_amdgcn_exp2f(2.8853900817779268f * x));
}

__device__ __forceinline__ unsigned short h2u(_Float16 h) {
    union { _Float16 f; unsigned short u; } cv; cv.f = h; return cv.u;
}

// ---------------- generic C = A@B^T (+ A2@B2^T) (+bias) (+relu), tile 64x64, K=128 ----
template<bool DUAL, bool RELU, bool BIAS>
__global__ __launch_bounds__(256)
void gemm_tn(const float* __restrict__ A, int lda,
             const float* __restrict__ B, int ldb,
             const float* __restrict__ A2, int lda2,
             const float* __restrict__ B2, int ldb2,
             const float* __restrict__ bias,
             float* __restrict__ C, int ldc, int K)
{
    __shared__ float As[32][68];
    __shared__ float Bs[32][68];
    const int t = threadIdx.x;
    const int tx = t & 15, ty = t >> 4;
    const int row0 = blockIdx.y * 64, col0 = blockIdx.x * 64;
    const int lm = t >> 2;           // 0..63
    const int lk = (t & 3) * 8;      // 0,8,16,24
    float acc[4][4] = {};
    const int npass = DUAL ? 2 : 1;
    for (int pass = 0; pass < npass; ++pass) {
        const float* Ap = pass ? A2 : A; const int ldap = pass ? lda2 : lda;
        const float* Bp = pass ? B2 : B; const int ldbp = pass ? ldb2 : ldb;
        for (int k0 = 0; k0 < K; k0 += 32) {
            __syncthreads();
            {
                const float* srcA = Ap + (size_t)(row0 + lm) * ldap + k0 + lk;
                float4 a0 = *(const float4*)(srcA);
                float4 a1 = *(const float4*)(srcA + 4);
                As[lk + 0][lm] = a0.x; As[lk + 1][lm] = a0.y; As[lk + 2][lm] = a0.z; As[lk + 3][lm] = a0.w;
                As[lk + 4][lm] = a1.x; As[lk + 5][lm] = a1.y; As[lk + 6][lm] = a1.z; As[lk + 7][lm] = a1.w;
                const float* srcB = Bp + (size_t)(col0 + lm) * ldbp + k0 + lk;
                float4 b0 = *(const float4*)(srcB);
                float4 b1 = *(const float4*)(srcB + 4);
                Bs[lk + 0][lm] = b0.x; Bs[lk + 1][lm] = b0.y; Bs[lk + 2][lm] = b0.z; Bs[lk + 3][lm] = b0.w;
                Bs[lk + 4][lm] = b1.x; Bs[lk + 5][lm] = b1.y; Bs[lk + 6][lm] = b1.z; Bs[lk + 7][lm] = b1.w;
            }
            __syncthreads();
            #pragma unroll
            for (int k = 0; k < 32; ++k) {
                float av[4], bv[4];
                *(float4*)av = *(const float4*)&As[k][ty * 4];
                *(float4*)bv = *(const float4*)&Bs[k][tx * 4];
                #pragma unroll
                for (int i = 0; i < 4; ++i)
                    #pragma unroll
                    for (int j = 0; j < 4; ++j)
                        acc[i][j] = fmaf(av[i], bv[j], acc[i][j]);
            }
        }
    }
    #pragma unroll
    for (int i = 0; i < 4; ++i) {
        const int r = row0 + ty * 4 + i;
        const int c = col0 + tx * 4;
        float vv[4];
        #pragma unroll
        for (int j = 0; j < 4; ++j) {
            float x = acc[i][j];
            if (BIAS) x += bias[c + j];
            if (RELU) x = fmaxf(x, 0.0f);
            vv[j] = x;
        }
        *(float4*)&C[(size_t)r * ldc + c] = *(float4*)vv;
    }
}

// ---------------- small prep kernels ----------------
__global__ void prep_hprev(const float* __restrict__ lstm_h, const float* __restrict__ masks,
                           float* __restrict__ hprev)
{
    int i = blockIdx.x * 256 + threadIdx.x;
    hprev[i] = lstm_h[i] * masks[i >> 7];
}

__global__ void lstm_pointwise(const float* __restrict__ gates,
                               const float* __restrict__ bih, const float* __restrict__ bhh,
                               const float* __restrict__ lstm_c, const float* __restrict__ masks,
                               float* __restrict__ h,
                               float* __restrict__ out_h, float* __restrict__ out_c)
{
    int idx = blockIdx.x * 256 + threadIdx.x;
    int r = idx >> 7, c = idx & 127;
    const float* g = gates + (size_t)r * G4;
    float gi = g[c]        + bih[c]        + bhh[c];
    float gf = g[128 + c]  + bih[128 + c]  + bhh[128 + c];
    float gg = g[256 + c]  + bih[256 + c]  + bhh[256 + c];
    float go = g[384 + c]  + bih[384 + c]  + bhh[384 + c];
    float cprev = lstm_c[idx] * masks[r];
    float cn = sigf(gf) * cprev + sigf(gi) * tanhf(gg);
    float hn = sigf(go) * tanhf(cn);
    h[idx] = hn;
    out_h[idx] = hn;
    out_c[idx] = cn;
}

// ---------------- persistent bidirectional GRU scan (MFMA, weights-stationary) --------
// 256 blocks (128 fwd + 128 bwd), 512 threads = 8 waves, 32 rows/block.
// Wave w owns h-columns [w*16, w*16+16) for all 3 gates. Whh stationary in registers
// (split-f16 hi + lo/1024, 3-MFMA product). U preloaded (24 regs); V rows {tt,tt+1}
// prefetched one step ahead. W_hard logits = 4th MFMA "gate" on wave 0 (one step
// delayed, reading h_{s-1} from LDS). Double-buffered h planes -> 1 barrier/step.
__global__ __launch_bounds__(512, 2)
void gru_scan(const float* __restrict__ WhhF, const float* __restrict__ WhhB,
              const float* __restrict__ bhhF, const float* __restrict__ bhhB,
              const float* __restrict__ Uf, const float* __restrict__ Vf,
              const float* __restrict__ Ub, const float* __restrict__ Vb,
              const float* __restrict__ Whard,
              float* __restrict__ partF, float* __restrict__ partB)
{
    __shared__ __align__(16) unsigned short hHi[2][32][LDSW];
    __shared__ __align__(16) unsigned short hLo[2][32][LDSW];

    const int t = threadIdx.x;
    const int dir = blockIdx.x >> 7;
    const int blk = blockIdx.x & 127;
    const int r0 = blk * 32;
    const int bbx = r0 >> 6;
    const int n0 = r0 & 63;
    const int w  = t >> 6;        // wave 0..7
    const int l  = t & 63;        // lane
    const int li = l & 15;
    const int lg = l >> 4;        // 0..3
    const int cl = w * 16 + li;   // owned h column 0..127

    const float* Whh = dir ? WhhB : WhhF;
    const float* bhh = dir ? bhhB : bhhF;
    const float* U   = dir ? Ub   : Uf;
    const float* V   = dir ? Vb   : Vf;
    float* part      = dir ? partB : partF;

    // stationary gate-weight fragments: B[k][n], n = cl, k = kt*32 + lg*8 + j
    f16x8 Bhi[3][4], Blo[3][4];
    #pragma unroll
    for (int g = 0; g < 3; ++g)
        #pragma unroll
        for (int kt = 0; kt < 4; ++kt) {
            const float* src = Whh + (size_t)(g * 128 + cl) * 128 + kt * 32 + lg * 8;
            #pragma unroll
            for (int j = 0; j < 8; ++j) {
                float wv = src[j];
                _Float16 hi = (_Float16)wv;
                _Float16 lo = (_Float16)((wv - (float)hi) * 1024.0f);
                Bhi[g][kt][j] = hi;
                Blo[g][kt][j] = lo;
            }
        }

    // W_hard pred fragments (wave 0): B[k][n=li<2], k = dir*128 + kt*32+lg*8+j
    f16x8 Phi[4], Plo[4];
    if (w == 0) {
        #pragma unroll
        for (int kt = 0; kt < 4; ++kt) {
            #pragma unroll
            for (int j = 0; j < 8; ++j) {
                float wv = (li < 2) ? Whard[li * 256 + dir * 128 + kt * 32 + lg * 8 + j] : 0.0f;
                _Float16 hi = (_Float16)wv;
                _Float16 lo = (_Float16)((wv - (float)hi) * 1024.0f);
                Phi[kt][j] = hi;
                Plo[kt][j] = lo;
            }
        }
    }

    const float bh_r = bhh[cl];
    const float bh_z = bhh[128 + cl];
    const float bh_n = bhh[256 + cl];

    // step-invariant U gate values (8 slots: row = rt*16 + lg*4 + rg, col = cl)
    float u_r[8], u_z[8], u_n[8];
    #pragma unroll
    for (int rt = 0; rt < 2; ++rt)
        #pragma unroll
        for (int rg = 0; rg < 4; ++rg) {
            const int idx = rt * 4 + rg;
            const int R = r0 + rt * 16 + lg * 4 + rg;
            const float* Ur = U + (size_t)R * G3;
            u_r[idx] = Ur[cl];
            u_z[idx] = Ur[128 + cl];
            u_n[idx] = Ur[256 + cl];
        }

    // V pipeline: rows {tt, tt+1}, prefetched
    const int vbase = bbx << 6;
    float v0r, v0z, v0n, v1r, v1z, v1n;
    {
        const int tt0 = dir ? (NM - 1) : 0;
        const float* Vr0 = V + (size_t)(vbase + tt0) * G3;
        const float* Vr1 = V + (size_t)(vbase + tt0 + 1) * G3;
        v0r = Vr0[cl]; v0z = Vr0[128 + cl]; v0n = Vr0[256 + cl];
        v1r = Vr1[cl]; v1z = Vr1[128 + cl]; v1n = Vr1[256 + cl];
    }

    for (int i = t; i < 2 * 32 * LDSW; i += 512) {
        (&hHi[0][0][0])[i] = 0;
        (&hLo[0][0][0])[i] = 0;
    }
    float hreg[8] = {0.f,0.f,0.f,0.f,0.f,0.f,0.f,0.f};

    int cur = 0;
    __syncthreads();

    for (int s = 0; s < NM; ++s) {
        const int tt = dir ? (NM - 1 - s) : s;

        // next-step V prefetch (hides under MFMA)
        float p0r, p0z, p0n, p1r, p1z, p1n;
        {
            const int sn = (s + 1 < NM) ? s + 1 : s;
            const int ttn = dir ? (NM - 1 - sn) : sn;
            const float* Vr0 = V + (size_t)(vbase + ttn) * G3;
            const float* Vr1 = V + (size_t)(vbase + ttn + 1) * G3;
            p0r = Vr0[cl]; p0z = Vr0[128 + cl]; p0n = Vr0[256 + cl];
            p1r = Vr1[cl]; p1z = Vr1[128 + cl]; p1n = Vr1[256 + cl];
        }

        f32x4 accA[3][2], accB[3][2], pA[2], pB[2];
        #pragma unroll
        for (int g = 0; g < 3; ++g)
            #pragma unroll
            for (int rt = 0; rt < 2; ++rt) {
                accA[g][rt] = (f32x4){0.f,0.f,0.f,0.f};
                accB[g][rt] = (f32x4){0.f,0.f,0.f,0.f};
            }
        pA[0] = pA[1] = pB[0] = pB[1] = (f32x4){0.f,0.f,0.f,0.f};

        #pragma unroll
        for (int kt = 0; kt < 4; ++kt) {
            f16x8 Ahi[2], Alo[2];
            const int koff = kt * 32 + lg * 8;
            #pragma unroll
            for (int rt = 0; rt < 2; ++rt) {
                const int arow = rt * 16 + li;
                Ahi[rt] = *(const f16x8*)&hHi[cur][arow][koff];
                Alo[rt] = *(const f16x8*)&hLo[cur][arow][koff];
            }
            #pragma unroll
            for (int g = 0; g < 3; ++g)
                #pragma unroll
                for (int rt = 0; rt < 2; ++rt) {
                    accA[g][rt] = __builtin_amdgcn_mfma_f32_16x16x32_f16(Ahi[rt], Bhi[g][kt], accA[g][rt], 0, 0, 0);
                    accB[g][rt] = __builtin_amdgcn_mfma_f32_16x16x32_f16(Alo[rt], Bhi[g][kt], accB[g][rt], 0, 0, 0);
                    accB[g][rt] = __builtin_amdgcn_mfma_f32_16x16x32_f16(Ahi[rt], Blo[g][kt], accB[g][rt], 0, 0, 0);
                }
            if (w == 0) {
                #pragma unroll
                for (int rt = 0; rt < 2; ++rt) {
                    pA[rt] = __builtin_amdgcn_mfma_f32_16x16x32_f16(Ahi[rt], Phi[kt], pA[rt], 0, 0, 0);
                    pB[rt] = __builtin_amdgcn_mfma_f32_16x16x32_f16(Alo[rt], Phi[kt], pB[rt], 0, 0, 0);
                    pB[rt] = __builtin_amdgcn_mfma_f32_16x16x32_f16(Ahi[rt], Plo[kt], pB[rt], 0, 0, 0);
                }
            }
        }

        // wave 0: store previous step's W_hard logits (computed from h_{s-1})
        if (w == 0 && s > 0 && li < 2) {
            const int ttp = dir ? (tt + 1) : (tt - 1);
            #pragma unroll
            for (int rt = 0; rt < 2; ++rt)
                #pragma unroll
                for (int rg = 0; rg < 4; ++rg) {
                    const int row = rt * 16 + lg * 4 + rg;
                    part[((size_t)(r0 + row) * NM + ttp) * 2 + li] =
                        pA[rt][rg] + pB[rt][rg] * 9.765625e-4f;
                }
        }

        // GRU pointwise epilogue (fast transcendentals)
        #pragma unroll
        for (int rt = 0; rt < 2; ++rt) {
            #pragma unroll
            for (int rg = 0; rg < 4; ++rg) {
                const int idx = rt * 4 + rg;
                const int row = rt * 16 + lg * 4 + rg;
                const int n = n0 + row;
                const bool up = (tt >= n);
                const float vr_ = up ? v1r : v0r;
                const float vz_ = up ? v1z : v0z;
                const float vn_ = up ? v1n : v0n;
                const float gr = accA[0][rt][rg] + accB[0][rt][rg] * 9.765625e-4f + bh_r;
                const float gz = accA[1][rt][rg] + accB[1][rt][rg] * 9.765625e-4f + bh_z;
                const float gn = accA[2][rt][rg] + accB[2][rt][rg] * 9.765625e-4f + bh_n;
                const float rr  = fsig(u_r[idx] + vr_ + gr);
                const float zz  = fsig(u_z[idx] + vz_ + gz);
                const float nn2 = ftanh(u_n[idx] + vn_ + rr * gn);
                hreg[idx] = (1.0f - zz) * nn2 + zz * hreg[idx];
            }
        }

        v0r = p0r; v0z = p0z; v0n = p0n;
        v1r = p1r; v1z = p1z; v1n = p1n;

        // write split h to the other buffer (readers are on buf[cur]; no race)
        const int nxt = cur ^ 1;
        #pragma unroll
        for (int rt = 0; rt < 2; ++rt)
            #pragma unroll
            for (int rg = 0; rg < 4; ++rg) {
                const int row = rt * 16 + lg * 4 + rg;
                const float hn = hreg[rt * 4 + rg];
                _Float16 hi = (_Float16)hn;
                _Float16 lo = (_Float16)((hn - (float)hi) * 1024.0f);
                hHi[nxt][row][cl] = h2u(hi);
                hLo[nxt][row][cl] = h2u(lo);
            }
        cur = nxt;
        __syncthreads();   // writes to buf[cur] visible before next step's reads
    }

    // final W_hard logits for the last step (h_{62} sits in buf[cur])
    if (w == 0) {
        f32x4 qA[2], qB[2];
        qA[0] = qA[1] = qB[0] = qB[1] = (f32x4){0.f,0.f,0.f,0.f};
        #pragma unroll
        for (int kt = 0; kt < 4; ++kt) {
            const int koff = kt * 32 + lg * 8;
            #pragma unroll
            for (int rt = 0; rt < 2; ++rt) {
                f16x8 Ah = *(const f16x8*)&hHi[cur][rt * 16 + li][koff];
                f16x8 Al = *(const f16x8*)&hLo[cur][rt * 16 + li][koff];
                qA[rt] = __builtin_amdgcn_mfma_f32_16x16x32_f16(Ah, Phi[kt], qA[rt], 0, 0, 0);
                qB[rt] = __builtin_amdgcn_mfma_f32_16x16x32_f16(Al, Phi[kt], qB[rt], 0, 0, 0);
                qB[rt] = __builtin_amdgcn_mfma_f32_16x16x32_f16(Ah, Plo[kt], qB[rt], 0, 0, 0);
            }
        }
        if (li < 2) {
            const int ttl = dir ? 0 : NM - 1;
            #pragma unroll
            for (int rt = 0; rt < 2; ++rt)
                #pragma unroll
                for (int rg = 0; rg < 4; ++rg) {
                    const int row = rt * 16 + lg * 4 + rg;
                    part[((size_t)(r0 + row) * NM + ttl) * 2 + li] =
                        qA[rt][rg] + qB[rt][rg] * 9.765625e-4f;
                }
        }
    }
}

// ---------------- hard gate + soft attention + action head ----------------
__global__ __launch_bounds__(128)
void attn_final(const float* __restrict__ h, const float* __restrict__ q,
                const float* __restrict__ kk,
                const float* __restrict__ partF, const float* __restrict__ partB,
                const float* __restrict__ bhard, const float* __restrict__ gum,
                const float* __restrict__ Wact, const float* __restrict__ bact,
                float* __restrict__ out_act, float* __restrict__ out_alp)
{
    const int r = blockIdx.x;
    const int bbx = r >> 6, n = r & 63;
    const int t = threadIdx.x;
    __shared__ float qsh[HH], wsh[NM], shh[HH], shx[HH];
    if (t < HH) { qsh[t] = q[(size_t)r * HH + t]; shh[t] = h[(size_t)r * HH + t]; }
    __syncthreads();
    if (t < 64) {
        float sc = -INFINITY;
        float hardv = 0.0f;
        if (t < NM) {
            const int idxm = t + (t >= n ? 1 : 0);
            const float4* kr = (const float4*)(kk + (size_t)((bbx << 6) + idxm) * HH);
            float s = 0.0f;
            #pragma unroll
            for (int j4 = 0; j4 < 32; ++j4) {
                float4 kv = kr[j4];
                float4 qv = *(const float4*)&qsh[j4 * 4];
                s += kv.x * qv.x + kv.y * qv.y + kv.z * qv.z + kv.w * qv.w;
            }
            sc = s * 0.088388347648318447f;   // 1/sqrt(128)
            const float2 pf = *(const float2*)(partF + ((size_t)r * NM + t) * 2);
            const float2 pb = *(const float2*)(partB + ((size_t)r * NM + t) * 2);
            const float2 gv = *(const float2*)(gum + ((size_t)r * NM + t) * 2);
            const float l0 = pf.x + pb.x + bhard[0] + gv.x;
            const float l1 = pf.y + pb.y + bhard[1] + gv.y;
            hardv = (l1 > l0) ? 1.0f : 0.0f;
        }
        float mx = sc;
        #pragma unroll
        for (int d = 32; d; d >>= 1) mx = fmaxf(mx, __shfl_xor(mx, d, 64));
        const float e = (t < NM) ? expf(sc - mx) : 0.0f;
        float sum = e;
        #pragma unroll
        for (int d = 32; d; d >>= 1) sum += __shfl_xor(sum, d, 64);
        if (t < NM) wsh[t] = hardv * e / sum;
    }
    __syncthreads();
    {
        const int j = t;
        float x = 0.0f;
        for (int m = 0; m < NM; ++m) {
            const int idxm = m + (m >= n ? 1 : 0);
            x = fmaf(wsh[m], h[(size_t)((bbx << 6) + idxm) * HH + j], x);
        }
        shx[j] = x;
    }
    __syncthreads();
    if (t < 16) {
        const float* wa = Wact + (size_t)t * 256;
        float acc = bact[t];
        #pragma unroll
        for (int j4 = 0; j4 < 32; ++j4) {
            float4 w1 = *(const float4*)&wa[j4 * 4];
            float4 hv = *(const float4*)&shh[j4 * 4];
            float4 w2 = *(const float4*)&wa[128 + j4 * 4];
            float4 xv = *(const float4*)&shx[j4 * 4];
            acc += w1.x * hv.x + w1.y * hv.y + w1.z * hv.z + w1.w * hv.w
                 + w2.x * xv.x + w2.y * xv.y + w2.z * xv.z + w2.w * xv.w;
        }
        float mx = acc; int am = t;
        #pragma unroll
        for (int d = 8; d; d >>= 1) {
            const float om = __shfl_xor(mx, d, 16);
            const int   oa = __shfl_xor(am, d, 16);
            if (om > mx || (om == mx && oa < am)) { mx = om; am = oa; }
        }
        const float e = expf(acc - mx);
        float sum = e;
        #pragma unroll
        for (int d = 8; d; d >>= 1) sum += __shfl_xor(sum, d, 16);
        if (t == 0) {
            out_act[r] = (float)am;
            out_alp[r] = -logf(sum);
        }
    }
}

// ---------------- launch ----------------
extern "C" void kernel_launch(void* const* d_in, const int* in_sizes, int n_in,
                              void* d_out, int out_size, void* d_ws, size_t ws_size,
                              hipStream_t stream)
{
    const float* obs    = (const float*)d_in[0];
    const float* lstm_h = (const float*)d_in[1];
    const float* lstm_c = (const float*)d_in[2];
    const float* masks  = (const float*)d_in[3];
    const float* W_enc  = (const float*)d_in[4];
    const float* b_enc  = (const float*)d_in[5];
    const float* lWih   = (const float*)d_in[6];
    const float* lWhh   = (const float*)d_in[7];
    const float* lbih   = (const float*)d_in[8];
    const float* lbhh   = (const float*)d_in[9];
    const float* gWihf  = (const float*)d_in[10];
    const float* gWhhf  = (const float*)d_in[11];
    const float* gbihf  = (const float*)d_in[12];
    const float* gbhhf  = (const float*)d_in[13];
    const float* gWihb  = (const float*)d_in[14];
    const float* gWhhb  = (const float*)d_in[15];
    const float* gbihb  = (const float*)d_in[16];
    const float* gbhhb  = (const float*)d_in[17];
    const float* Whard  = (const float*)d_in[18];
    const float* bhard  = (const float*)d_in[19];
    const float* Wq     = (const float*)d_in[20];
    const float* Wk     = (const float*)d_in[21];
    const float* Wact   = (const float*)d_in[22];
    const float* bact   = (const float*)d_in[23];
    const float* gum    = (const float*)d_in[24];

    float* W = (float*)d_ws;
    float* h     = W; W += (size_t)BN_ * HH;
    float* hprev = W; W += (size_t)BN_ * HH;
    float* henc  = W; W += (size_t)BN_ * HH;
    float* gates = W; W += (size_t)BN_ * G4;
    float* Uf    = W; W += (size_t)BN_ * G3;
    float* Vf    = W; W += (size_t)BN_ * G3;
    float* Ub    = W; W += (size_t)BN_ * G3;
    float* Vb    = W; W += (size_t)BN_ * G3;
    float* partF = W; W += (size_t)BN_ * NM * 2;
    float* partB = W; W += (size_t)BN_ * NM * 2;
    float* qq    = W; W += (size_t)BN_ * HH;
    float* kk    = W; W += (size_t)BN_ * HH;

    float* out_f   = (float*)d_out;
    float* out_act = out_f;                       // 4096
    float* out_alp = out_act + BN_;               // 4096
    float* out_h   = out_alp + BN_;               // 4096*128
    float* out_c   = out_h + (size_t)BN_ * HH;    // 4096*128

    prep_hprev<<<BN_ * HH / 256, 256, 0, stream>>>(lstm_h, masks, hprev);
    gemm_tn<false, true, true><<<dim3(HH / 64, BN_ / 64), 256, 0, stream>>>(
        obs, OBS_, W_enc, OBS_, nullptr, 0, nullptr, 0, b_enc, henc, HH, OBS_);
    gemm_tn<true, false, false><<<dim3(G4 / 64, BN_ / 64), 256, 0, stream>>>(
        henc, HH, lWih, HH, hprev, HH, lWhh, HH, nullptr, gates, G4, HH);
    lstm_pointwise<<<BN_ * HH / 256, 256, 0, stream>>>(gates, lbih, lbhh, lstm_c, masks,
                                                       h, out_h, out_c);
    gemm_tn<false, false, true><<<dim3(G3 / 64, BN_ / 64), 256, 0, stream>>>(
        h, HH, gWihf, 2 * HH, nullptr, 0, nullptr, 0, gbihf, Uf, G3, HH);
    gemm_tn<false, false, false><<<dim3(G3 / 64, BN_ / 64), 256, 0, stream>>>(
        h, HH, gWihf + HH, 2 * HH, nullptr, 0, nullptr, 0, nullptr, Vf, G3, HH);
    gemm_tn<false, false, true><<<dim3(G3 / 64, BN_ / 64), 256, 0, stream>>>(
        h, HH, gWihb, 2 * HH, nullptr, 0, nullptr, 0, gbihb, Ub, G3, HH);
    gemm_tn<false, false, false><<<dim3(G3 / 64, BN_ / 64), 256, 0, stream>>>(
        h, HH, gWihb + HH, 2 * HH, nullptr, 0, nullptr, 0, nullptr, Vb, G3, HH);
    gemm_tn<false, false, false><<<dim3(HH / 64, BN_ / 64), 256, 0, stream>>>(
        h, HH, Wq, HH, nullptr, 0, nullptr, 0, nullptr, qq, HH, HH);
    gemm_tn<false, false, false><<<dim3(HH / 64, BN_ / 64), 256, 0, stream>>>(
        h, HH, Wk, HH, nullptr, 0, nullptr, 0, nullptr, kk, HH, HH);
    gru_scan<<<256, 512, 0, stream>>>(gWhhf, gWhhb, gbhhf, gbhhb, Uf, Vf, Ub, Vb,
                                      Whard, partF, partB);
    attn_final<<<BN_, 128, 0, stream>>>(h, qq, kk, partF, partB, bhard, gum,
                                        Wact, bact, out_act, out_alp);
}